// Round 5
// baseline (207.923 us; speedup 1.0000x reference)
//
#include <hip/hip_runtime.h>
#include <hip/hip_bf16.h>

typedef short bf16x8 __attribute__((ext_vector_type(8)));
typedef float f32x4 __attribute__((ext_vector_type(4)));

#define N_IMG 64
#define CIN   256
#define COUT  256
#define HH    28
#define WW    28
#define PH    30
#define PW    30
#define M_TOT (N_IMG*HH*WW)          // 50176
#define OUT_ELEMS (N_IMG*COUT*HH*WW) // 12845056

// workspace layout (bytes)
#define XT_ELEMS   ((size_t)N_IMG*PH*PW*CIN)       // 14745600 bf16
#define WT_OFF     (XT_ELEMS*2)                    // 29491200
#define WT_ELEMS   ((size_t)9*COUT*CIN)            // 589824 bf16
#define BQ_OFF     (WT_OFF + WT_ELEMS*2)           // 30670848

#define GLD16(g, l) __builtin_amdgcn_global_load_lds( \
    (const __attribute__((address_space(1))) void*)(g), \
    (__attribute__((address_space(3))) void*)(l), 16, 0, 0)

// ---------------------------------------------------------------------------
// Kernel 1: x int32 NCHW -> padded bf16 NHWC [N][30][30][256]
__global__ __launch_bounds__(256) void transform_x(const int* __restrict__ xq,
                                                   unsigned short* __restrict__ xt) {
    __shared__ float xs[CIN*29];   // padded stride 29 -> no bank conflicts
    const int b = blockIdx.x;
    const int n = b / PH, py = b % PH;
    const int t = threadIdx.x;
    unsigned short* dst = xt + ((size_t)(n*PH + py))*PW*CIN;
    if (py == 0 || py == PH-1) {
        for (int i = t; i < PW*CIN; i += 256) dst[i] = 0;
        return;
    }
    const int h = py - 1;
    const int* src = xq + (size_t)n*CIN*HH*WW + h*WW;
    for (int i = t; i < CIN*WW; i += 256) {
        const int ci = i / WW, w = i % WW;
        xs[ci*29 + w] = (float)src[ci*HH*WW + w];
    }
    __syncthreads();
    for (int i = t; i < PW*CIN; i += 256) {
        const int px = i / CIN, ci = i % CIN;
        float v = (px == 0 || px == PW-1) ? 0.f : xs[ci*29 + (px-1)];
        dst[px*CIN + ci] = (unsigned short)(__float_as_uint(v) >> 16);
    }
}

// ---------------------------------------------------------------------------
// Kernel 2: per-channel weight quant + bias quant + scale_out to d_out tail.
// wt layout: [tap(9)][co(256)][ci(256)] bf16   (values in [-128,127], exact)
__global__ __launch_bounds__(256) void quant_w(const float* __restrict__ weight,
                                               const float* __restrict__ scale_x,
                                               const float* __restrict__ bias,
                                               unsigned short* __restrict__ wt,
                                               int* __restrict__ bq,
                                               float* __restrict__ out_tail) {
    __shared__ float red[256];
    const int co = blockIdx.x, t = threadIdx.x;
    const float* wrow = weight + (size_t)co*CIN*9;
    float wv[9];
    float mx = 0.f;
    for (int it = 0; it < 9; ++it) {
        float v = wrow[it*256 + t];
        wv[it] = v;
        mx = fmaxf(mx, fabsf(v));
    }
    red[t] = mx;
    __syncthreads();
    for (int s = 128; s > 0; s >>= 1) {
        if (t < s) red[t] = fmaxf(red[t], red[t+s]);
        __syncthreads();
    }
    const float scale = fmaxf(red[0], 1e-8f) / 127.f;
    for (int it = 0; it < 9; ++it) {
        const int i = it*256 + t;          // index over [ci][r][s]
        const int ci = i / 9, rs = i % 9;
        float q = rintf(wv[it] / scale);   // rintf = round-half-even = jnp.round
        q = fminf(fmaxf(q, -128.f), 127.f);
        wt[((size_t)rs*COUT + co)*CIN + ci] = (unsigned short)(__float_as_uint(q) >> 16);
    }
    if (t == 0) {
        const float so = scale * scale_x[0];
        out_tail[co] = so;
        bq[co] = (int)rintf(bias[co] / so);
    }
}

// ---------------------------------------------------------------------------
// Kernel 3: implicit-GEMM conv, m97 structure + 2-phase double-buffered LDS.
// C[co][m] = sum_{tap,ci} W[co][ci,tap] * X[ci,tap][m]
// Block tile: 128 co x 128 m, BK=32, 4 waves (2x2), each wave 64x64 (acc[4][4]).
// K-stream: 72 steps (9 taps x 8 ci-chunks). STAGE(kt+1) issues before
// compute(kt); the single __syncthreads (vmcnt+lgkm drain) lands after ~300cy
// of ds_read+MFMA has covered the load latency.   [T3 minimum-2-phase recipe]
__global__ __launch_bounds__(256) void conv_mfma(const unsigned short* __restrict__ xt,
                                                 const unsigned short* __restrict__ wt,
                                                 const int* __restrict__ bq,
                                                 float* __restrict__ out) {
    __shared__ short Ash[2][4096];  // W tile: [kc(4)][row 128][8]
    __shared__ short Bsh[2][4096];  // X tile: same chunked layout
    const int t = threadIdx.x;
    const int lane = t & 63, wid = t >> 6;
    const int wr = wid >> 1, wc = wid & 1;         // wave grid: 2 (co) x 2 (m)
    const int m0 = blockIdx.x * 128, co0 = blockIdx.y * 128;

    // staging geometry: wave wid writes chunk wid (k-chunk wid>>1, row-half wid&1)
    const int srow = (wid & 1)*64 + lane;
    const int kc0  = wid >> 1;

    const int m = m0 + srow;
    const int n = m / 784, hw = m % 784;
    const int h = hw / 28, w = hw % 28;
    const unsigned short* bsrc0 = xt + ((size_t)((n*PH + h)*PW + w))*CIN + kc0*8;
    const unsigned short* asrc0 = wt + (size_t)(co0 + srow)*CIN + kc0*8;

    f32x4 acc[4][4] = {};
    const int kg = lane >> 4, lr = lane & 15;
    const int ar0 = (wr*64 + lr)*8 + kg*1024;      // A frag base (shorts)
    const int br0 = (wc*64 + lr)*8 + kg*1024;      // B frag base

    // stage K-step KT into buffer BUF (4x global_load_lds width-16)
#define STAGE(BUF, KT) do { \
    const int tap_ = (KT) >> 3, ci_ = ((KT) & 7) << 5; \
    const int r_ = (tap_*171) >> 9, s_ = tap_ - r_*3; \
    const unsigned short* at_ = asrc0 + tap_*(COUT*CIN) + ci_; \
    const unsigned short* bt_ = bsrc0 + (r_*PW + s_)*CIN + ci_; \
    GLD16(at_,      &Ash[BUF][wid*512]); \
    GLD16(at_ + 16, &Ash[BUF][2048 + wid*512]); \
    GLD16(bt_,      &Bsh[BUF][wid*512]); \
    GLD16(bt_ + 16, &Bsh[BUF][2048 + wid*512]); \
} while (0)

#define COMPUTE(BUF) do { \
    bf16x8 af[4], bf[4]; \
    _Pragma("unroll") \
    for (int f = 0; f < 4; ++f) { \
        af[f] = *(const bf16x8*)&Ash[BUF][ar0 + f*128]; \
        bf[f] = *(const bf16x8*)&Bsh[BUF][br0 + f*128]; \
    } \
    _Pragma("unroll") \
    for (int fm = 0; fm < 4; ++fm) \
        _Pragma("unroll") \
        for (int fn = 0; fn < 4; ++fn) \
            acc[fm][fn] = __builtin_amdgcn_mfma_f32_16x16x32_bf16( \
                af[fm], bf[fn], acc[fm][fn], 0, 0, 0); \
} while (0)

    STAGE(0, 0);
    __syncthreads();                 // drain prologue stage
    int cur = 0;
#pragma unroll 1
    for (int kt = 0; kt < 71; ++kt) {
        STAGE(cur ^ 1, kt + 1);      // issue next step's loads first
        COMPUTE(cur);                // ds_read + 16 MFMA hide the latency
        __syncthreads();             // vmcnt(0)+lgkm drain once per step
        cur ^= 1;
    }
    COMPUTE(cur);                    // epilogue step, no prefetch

    // epilogue: D row = co (kg*4+rg), col = m (lr); 64B coalesced runs
#pragma unroll
    for (int fm = 0; fm < 4; ++fm) {
        const int co = co0 + wr*64 + fm*16 + kg*4;
        float bqv[4];
#pragma unroll
        for (int rg = 0; rg < 4; ++rg) bqv[rg] = (float)bq[co + rg];
#pragma unroll
        for (int fn = 0; fn < 4; ++fn) {
            const int mm = m0 + wc*64 + fn*16 + lr;
            const int nn = mm / 784, hw2 = mm % 784;
#pragma unroll
            for (int rg = 0; rg < 4; ++rg)
                out[((size_t)nn*COUT + co + rg)*784 + hw2] = acc[fm][fn][rg] + bqv[rg];
        }
    }
#undef STAGE
#undef COMPUTE
}

// ---------------------------------------------------------------------------
extern "C" void kernel_launch(void* const* d_in, const int* in_sizes, int n_in,
                              void* d_out, int out_size, void* d_ws, size_t ws_size,
                              hipStream_t stream) {
    const int*   xq      = (const int*)d_in[0];
    const float* scale_x = (const float*)d_in[1];
    const float* weight  = (const float*)d_in[2];
    const float* bias    = (const float*)d_in[3];
    float* out = (float*)d_out;

    unsigned short* xt = (unsigned short*)d_ws;
    unsigned short* wt = (unsigned short*)((char*)d_ws + WT_OFF);
    int*            bq = (int*)((char*)d_ws + BQ_OFF);

    hipLaunchKernelGGL(transform_x, dim3(N_IMG*PH), dim3(256), 0, stream, xq, xt);
    hipLaunchKernelGGL(quant_w, dim3(COUT), dim3(256), 0, stream,
                       weight, scale_x, bias, wt, bq, out + OUT_ELEMS);
    hipLaunchKernelGGL(conv_mfma, dim3(M_TOT/128, COUT/128), dim3(256), 0, stream,
                       xt, wt, bq, out);
}

// Round 6
// 106.223 us; speedup vs baseline: 1.9574x; 1.9574x over previous
//
#include <hip/hip_runtime.h>
#include <hip/hip_bf16.h>

typedef short bf16x8 __attribute__((ext_vector_type(8)));
typedef float f32x4 __attribute__((ext_vector_type(4)));

#define N_IMG 64
#define CIN   256
#define COUT  256
#define HH    28
#define WW    28
#define PH    30
#define PW    30
#define M_TOT (N_IMG*HH*WW)          // 50176
#define OUT_ELEMS (N_IMG*COUT*HH*WW) // 12845056

// workspace layout (bytes)
#define XT_ELEMS   ((size_t)N_IMG*PH*PW*CIN)       // 14745600 bf16
#define WT_OFF     (XT_ELEMS*2)                    // 29491200
#define WT_ELEMS   ((size_t)9*COUT*CIN)            // 589824 bf16
#define BQ_OFF     (WT_OFF + WT_ELEMS*2)           // 30670848

#define GLD16(g, l) __builtin_amdgcn_global_load_lds( \
    (const __attribute__((address_space(1))) void*)(g), \
    (__attribute__((address_space(3))) void*)(l), 16, 0, 0)

// ---------------------------------------------------------------------------
// Kernel 1: x int32 NCHW -> padded bf16 NHWC [N][30][30][256]
__global__ __launch_bounds__(256) void transform_x(const int* __restrict__ xq,
                                                   unsigned short* __restrict__ xt) {
    __shared__ float xs[CIN*29];   // padded stride 29 -> no bank conflicts
    const int b = blockIdx.x;
    const int n = b / PH, py = b % PH;
    const int t = threadIdx.x;
    unsigned short* dst = xt + ((size_t)(n*PH + py))*PW*CIN;
    if (py == 0 || py == PH-1) {
        for (int i = t; i < PW*CIN; i += 256) dst[i] = 0;
        return;
    }
    const int h = py - 1;
    const int* src = xq + (size_t)n*CIN*HH*WW + h*WW;
    for (int i = t; i < CIN*WW; i += 256) {
        const int ci = i / WW, w = i % WW;
        xs[ci*29 + w] = (float)src[ci*HH*WW + w];
    }
    __syncthreads();
    for (int i = t; i < PW*CIN; i += 256) {
        const int px = i / CIN, ci = i % CIN;
        float v = (px == 0 || px == PW-1) ? 0.f : xs[ci*29 + (px-1)];
        dst[px*CIN + ci] = (unsigned short)(__float_as_uint(v) >> 16);
    }
}

// ---------------------------------------------------------------------------
// Kernel 2: per-channel weight quant + bias quant + scale_out to d_out tail.
// wt layout: [tap(9)][co(256)][ci(256)] bf16   (values in [-128,127], exact)
__global__ __launch_bounds__(256) void quant_w(const float* __restrict__ weight,
                                               const float* __restrict__ scale_x,
                                               const float* __restrict__ bias,
                                               unsigned short* __restrict__ wt,
                                               int* __restrict__ bq,
                                               float* __restrict__ out_tail) {
    __shared__ float red[256];
    const int co = blockIdx.x, t = threadIdx.x;
    const float* wrow = weight + (size_t)co*CIN*9;
    float wv[9];
    float mx = 0.f;
    for (int it = 0; it < 9; ++it) {
        float v = wrow[it*256 + t];
        wv[it] = v;
        mx = fmaxf(mx, fabsf(v));
    }
    red[t] = mx;
    __syncthreads();
    for (int s = 128; s > 0; s >>= 1) {
        if (t < s) red[t] = fmaxf(red[t], red[t+s]);
        __syncthreads();
    }
    const float scale = fmaxf(red[0], 1e-8f) / 127.f;
    for (int it = 0; it < 9; ++it) {
        const int i = it*256 + t;          // index over [ci][r][s]
        const int ci = i / 9, rs = i % 9;
        float q = rintf(wv[it] / scale);   // rintf = round-half-even = jnp.round
        q = fminf(fmaxf(q, -128.f), 127.f);
        wt[((size_t)rs*COUT + co)*CIN + ci] = (unsigned short)(__float_as_uint(q) >> 16);
    }
    if (t == 0) {
        const float so = scale * scale_x[0];
        out_tail[co] = so;
        bq[co] = (int)rintf(bias[co] / so);
    }
}

// ---------------------------------------------------------------------------
// Kernel 3: implicit-GEMM conv, big-tile deep-work structure.
//   C[co][m] = sum_{tap,ci} W[co][ci,tap] * X[ci,tap][m]
// BM=256 (ALL co) x BN=256 (m), BK=32. 512 threads = 8 waves (2 co x 4 m),
// per-wave 128x64 output = acc[8][4]; 32 MFMA + 12 ds_read_b128 per K-tile
// per wave; ONE s_barrier per K-tile. 72 K-tiles (9 taps x 8 ci-chunks).
// LDS: 2 buffers x (A 16KB + B 16KB) = 64KB, row-major [row][32] bf16 (64B
// rows -> frag reads are at the 8-access/bank floor, no swizzle needed;
// global_load_lds dest stays linear). stage(t+1) issues right after
// barrier(t); the vmcnt(0) drain at top of t+1 is ~1300cy after issue.
__global__ __launch_bounds__(512, 1) void conv_mfma(const unsigned short* __restrict__ xt,
                                                    const unsigned short* __restrict__ wt,
                                                    const int* __restrict__ bq,
                                                    float* __restrict__ out) {
    __shared__ short Ash[2*8192];   // [buf][row 256][k 32]
    __shared__ short Bsh[2*8192];
    const int d = threadIdx.x;
    const int w8 = d >> 6;                   // wave id 0..7 (wave-uniform)
    const int lane = d & 63, lr = lane & 15, kg = lane >> 4;
    const int wm = w8 >> 2, wn = w8 & 3;     // wave grid: 2 (co) x 4 (m)
    const int m0 = blockIdx.x << 8;

    // ---- staging sources: thread d covers rows (d>>2)+r*128, k-bytes (d&3)*16
    const int sr = d >> 2;                   // 0..127
    const int sk = (d & 3) << 3;             // element offset 0,8,16,24
    const unsigned short* aS = wt + sr*CIN + sk;   // + tap<<16 + c<<5 (+32768 for r1)
    const unsigned short* bS0;
    const unsigned short* bS1;
    {
        int m = m0 + sr;
        int n = m / 784, hw = m % 784, h = hw / 28, wq = hw % 28;
        bS0 = xt + ((size_t)((n*PH + h)*PW + wq))*CIN + sk;
        m += 128;
        n = m / 784; hw = m % 784; h = hw / 28; wq = hw % 28;
        bS1 = xt + ((size_t)((n*PH + h)*PW + wq))*CIN + sk;
    }
    // LDS dest (wave-uniform base; HW adds lane*16B): shorts w8*512 (+4096 r1)
    const int dst0 = w8 << 9;

    f32x4 acc[8][4] = {};

    // per-lane fragment read bases (shorts): row*32 + kg*8
    const int arb = (wm*128 + lr)*32 + kg*8;
    const int brb = (wn*64  + lr)*32 + kg*8;

#define STAGE(T_, P_) do { \
    const int tap_ = (T_) >> 3, c_ = (T_) & 7; \
    const int r3_ = (tap_*171) >> 9; \
    const int ao_ = (tap_ << 16) + (c_ << 5); \
    const int bo_ = ((r3_*PW + (tap_ - r3_*3)) << 8) + (c_ << 5); \
    GLD16(aS + ao_,          Ash + (P_)*8192 + dst0); \
    GLD16(aS + ao_ + 32768,  Ash + (P_)*8192 + dst0 + 4096); \
    GLD16(bS0 + bo_,         Bsh + (P_)*8192 + dst0); \
    GLD16(bS1 + bo_,         Bsh + (P_)*8192 + dst0 + 4096); \
} while (0)

#define COMPUTE(P_) do { \
    const short* A_ = Ash + (P_)*8192; \
    const short* B_ = Bsh + (P_)*8192; \
    bf16x8 af[8], bf[4]; \
    _Pragma("unroll") \
    for (int mr = 0; mr < 8; ++mr) af[mr] = *(const bf16x8*)&A_[arb + mr*512]; \
    _Pragma("unroll") \
    for (int nr = 0; nr < 4; ++nr) bf[nr] = *(const bf16x8*)&B_[brb + nr*512]; \
    _Pragma("unroll") \
    for (int mr = 0; mr < 8; ++mr) \
        _Pragma("unroll") \
        for (int nr = 0; nr < 4; ++nr) \
            acc[mr][nr] = __builtin_amdgcn_mfma_f32_16x16x32_bf16( \
                af[mr], bf[nr], acc[mr][nr], 0, 0, 0); \
} while (0)

#define SYNCPT() do { \
    asm volatile("s_waitcnt vmcnt(0) lgkmcnt(0)" ::: "memory"); \
    __builtin_amdgcn_s_barrier(); \
    __builtin_amdgcn_sched_barrier(0); \
} while (0)

    STAGE(0, 0);
#pragma unroll 1
    for (int tt = 0; tt < 72; tt += 2) {
        SYNCPT();                      // tile tt landed (issued ~1 iter ago)
        STAGE(tt + 1, 1);              // into buf1 (tile tt-1's buffer, free)
        COMPUTE(0);                    // tile tt from buf0
        SYNCPT();                      // tile tt+1 landed
        if (tt < 70) STAGE(tt + 2, 0); // into buf0
        COMPUTE(1);                    // tile tt+1 from buf1
    }

    // epilogue: D row = co (kg*4+rg), col = m (lr); 64B coalesced runs
#pragma unroll
    for (int nr = 0; nr < 4; ++nr) {
        const int mm = m0 + wn*64 + nr*16 + lr;
        const int nn = mm / 784, hw2 = mm % 784;
        float* orow = out + (size_t)nn*COUT*784 + hw2;
#pragma unroll
        for (int mr = 0; mr < 8; ++mr) {
            const int co = wm*128 + mr*16 + kg*4;
#pragma unroll
            for (int rg = 0; rg < 4; ++rg)
                orow[(size_t)(co + rg)*784] = acc[mr][nr][rg] + (float)bq[co + rg];
        }
    }
#undef STAGE
#undef COMPUTE
#undef SYNCPT
}

// ---------------------------------------------------------------------------
extern "C" void kernel_launch(void* const* d_in, const int* in_sizes, int n_in,
                              void* d_out, int out_size, void* d_ws, size_t ws_size,
                              hipStream_t stream) {
    const int*   xq      = (const int*)d_in[0];
    const float* scale_x = (const float*)d_in[1];
    const float* weight  = (const float*)d_in[2];
    const float* bias    = (const float*)d_in[3];
    float* out = (float*)d_out;

    unsigned short* xt = (unsigned short*)d_ws;
    unsigned short* wt = (unsigned short*)((char*)d_ws + WT_OFF);
    int*            bq = (int*)((char*)d_ws + BQ_OFF);

    hipLaunchKernelGGL(transform_x, dim3(N_IMG*PH), dim3(256), 0, stream, xq, xt);
    hipLaunchKernelGGL(quant_w, dim3(COUT), dim3(256), 0, stream,
                       weight, scale_x, bias, wt, bq, out + OUT_ELEMS);
    hipLaunchKernelGGL(conv_mfma, dim3(M_TOT/256), dim3(512), 0, stream,
                       xt, wt, bq, out);
}